// Round 8
// baseline (62.258 us; speedup 1.0000x reference)
//
#include <hip/hip_runtime.h>

#define N_ROWS 14400
#define M_COLS 1600
#define KDIM   256
#define GRID_X 25           // 1600 / 64 col-tiles (exact)
#define GRID_Y 113          // ceil(14400/128) row-tiles
#define NWG    (GRID_X * GRID_Y)   // 2825

typedef __attribute__((ext_vector_type(8))) short bf16x8;
typedef __attribute__((ext_vector_type(4))) float f32x4;

__device__ __forceinline__ short f2bf(float x) {
  union { float f; unsigned u; } v; v.f = x;
  unsigned r = v.u + 0x7FFFu + ((v.u >> 16) & 1u);   // RNE to bf16
  return (short)(r >> 16);
}

__device__ __forceinline__ void gload_lds16(const void* g, void* l) {
  __builtin_amdgcn_global_load_lds(
      (const __attribute__((address_space(1))) void*)g,
      (__attribute__((address_space(3))) void*)l, 16, 0, 0);
}

// One WAVE per row; lane handles 4 consecutive floats (float4 in, short4 out).
__global__ __launch_bounds__(256) void prep_kernel(
    const float* __restrict__ logits, const float* __restrict__ embs,
    short* __restrict__ probB, short* __restrict__ embB) {
  const int row = blockIdx.x * 4 + (threadIdx.x >> 6);
  const int lane = threadIdx.x & 63;
  if (row < N_ROWS) {
    const float4 x = ((const float4*)(logits + (size_t)row * KDIM))[lane];
    float s = x.x * x.x + x.y * x.y + x.z * x.z + x.w * x.w;
#pragma unroll
    for (int o = 32; o > 0; o >>= 1) s += __shfl_xor(s, o, 64);
    const float scale = __builtin_amdgcn_rsqf(s);
    short4 o4;
    o4.x = f2bf(x.x * scale); o4.y = f2bf(x.y * scale);
    o4.z = f2bf(x.z * scale); o4.w = f2bf(x.w * scale);
    ((short4*)(probB + (size_t)row * KDIM))[lane] = o4;
  } else {
    const int r = row - N_ROWS;   // grid sized exactly, no overflow
    const float4 x = ((const float4*)(embs + (size_t)r * KDIM))[lane];
    short4 o4;
    o4.x = f2bf(x.x); o4.y = f2bf(x.y); o4.z = f2bf(x.z); o4.w = f2bf(x.w);
    ((short4*)(embB + (size_t)r * KDIM))[lane] = o4;
  }
}

// 128x64 tile GEMM (bf16 MFMA) + fused bbox-L1 + GIoU + sigmoid epilogue.
// - acc[4][2] = 32 AGPR; arch VGPR compiler-chosen (~96). No min-waves clamp
//   (r2/r4: forcing VGPR=64 serializes the epilogue).
// - LDS GEMM tiles XOR-swizzled -> 0 bank conflicts.
// - BARRIER-FREE epilogue: per-wave ping-pong transpose buffers (stride-35
//   pad) ordered by wave-local s_waitcnt lgkmcnt(0). r7's per-chunk
//   __syncthreads each forced a full vmcnt(0) drain of outstanding NT
//   stores (HBM latency) - the dominant stall. NT stores now stream freely.
// - dwordx4 NT stores, full 128B lines.
// - Bijective XCD-aware block swizzle for A-panel L2 reuse.
__global__ __launch_bounds__(256) void cost_kernel(
    const short* __restrict__ probB, const short* __restrict__ embB,
    const float* __restrict__ pbox, const float* __restrict__ tbox,
    float* __restrict__ out) {
  __shared__ __align__(16) char smem[30720];
  short* const As = (short*)smem;                 // [128*64] 16 KB
  short* const Bs = (short*)(smem + 16384);       // [64*64]   8 KB
  f32x4* const rowcc = (f32x4*)(smem + 24576);    // [128]     2 KB
  f32x4* const rowxy = rowcc + 128;               // [128]     2 KB
  f32x4* const colcc = rowxy + 128;               // [64]      1 KB
  f32x4* const colxy = colcc + 64;                // [64]      1 KB

  const int t = threadIdx.x;
  const int lane = t & 63;
  const int wid = t >> 6;
  const int wr = wid >> 1;          // wave row 0..1 (64-row band)
  const int wc = wid & 1;           // wave col 0..1 (32-col band)
  // Per-wave transpose scratch (overlays dead As/Bs after final K barrier):
  // 2 ping-pong bufs of 16x35 floats per wave.
  float* const twbuf = (float*)smem + wid * 1120;

  // Bijective XCD swizzle (m204): 8 XCDs, NWG=2825 (q=353, r=1).
  const int orig = blockIdx.x;
  const int xcd = orig & 7;
  const int rem = orig >> 3;
  const int q = NWG >> 3, r = NWG & 7;
  const int wgid = (xcd < r ? xcd * (q + 1) : r * (q + 1) + (xcd - r) * q) + rem;
  const int bx = wgid % GRID_X;
  const int by = wgid / GRID_X;
  const int rowBase = by * 128;     // N (pred) direction
  const int colBase = bx * 64;      // M (tgt) direction; always in-range

  // Stage per-tile box data (cols need no clamp: 1600 % 64 == 0).
  if (t < 128) {
    const int idx = rowBase + t;
    const int ci = idx < N_ROWS ? idx : N_ROWS - 1;
    const float4 bb = ((const float4*)pbox)[ci];
    rowcc[t] = (f32x4){bb.x, bb.y, bb.z, bb.w};
    rowxy[t] = (f32x4){fmaf(-0.5f, bb.z, bb.x), fmaf(-0.5f, bb.w, bb.y),
                       fmaf(0.5f, bb.z, bb.x), fmaf(0.5f, bb.w, bb.y)};
  } else if (t < 192) {
    const int c = t - 128;
    const float4 bb = ((const float4*)tbox)[colBase + c];
    colcc[c] = (f32x4){bb.x, bb.y, bb.z, bb.w};
    colxy[c] = (f32x4){fmaf(-0.5f, bb.z, bb.x), fmaf(-0.5f, bb.w, bb.y),
                       fmaf(0.5f, bb.z, bb.x), fmaf(0.5f, bb.w, bb.y)};
  }

  f32x4 acc[4][2];
#pragma unroll
  for (int i = 0; i < 4; ++i)
#pragma unroll
    for (int j = 0; j < 2; ++j) acc[i][j] = (f32x4){0.f, 0.f, 0.f, 0.f};

  // Pre-swizzled source granule: lane l stages granule (l&7)^(l>>3) so the
  // swizzled READ (g ^ row&7) sees linear data.
  const int swz = (lane & 7) ^ (lane >> 3);
  const int rbase = wid * 8 + (lane >> 3);   // staging row within 32-row group

  // K-loop: 4 tiles of BK=64.
  for (int kt = 0; kt < 4; ++kt) {
    const int k0 = kt * 64 + swz * 8;
#pragma unroll
    for (int i = 0; i < 4; ++i) {            // A: 128 rows
      int gr = rowBase + i * 32 + rbase;
      if (gr > N_ROWS - 1) gr = N_ROWS - 1;
      gload_lds16(probB + (size_t)gr * KDIM + k0, As + (i * 32 + wid * 8) * 64);
    }
#pragma unroll
    for (int i = 0; i < 2; ++i) {            // B: 64 rows (cols), no clamp
      const int gc = colBase + i * 32 + rbase;
      gload_lds16(embB + (size_t)gc * KDIM + k0, Bs + (i * 32 + wid * 8) * 64);
    }
    __syncthreads();
#pragma unroll
    for (int kk = 0; kk < 2; ++kk) {
      bf16x8 af[4], bfr[2];
      const int g = kk * 4 + (lane >> 4);    // 16B granule index 0..7
#pragma unroll
      for (int mi = 0; mi < 4; ++mi) {
        const int row = wr * 64 + mi * 16 + (lane & 15);
        af[mi] = *(const bf16x8*)(As + row * 64 + ((g ^ (row & 7)) * 8));
      }
#pragma unroll
      for (int ni = 0; ni < 2; ++ni) {
        const int row = wc * 32 + ni * 16 + (lane & 15);
        bfr[ni] = *(const bf16x8*)(Bs + row * 64 + ((g ^ (row & 7)) * 8));
      }
#pragma unroll
      for (int mi = 0; mi < 4; ++mi)
#pragma unroll
        for (int ni = 0; ni < 2; ++ni)
          acc[mi][ni] = __builtin_amdgcn_mfma_f32_16x16x32_bf16(
              af[mi], bfr[ni], acc[mi][ni], 0, 0, 0);
    }
    __syncthreads();   // last one also protects the twbuf overlay
  }

  // Barrier-free fused epilogue.
  const float LOG2E = 1.44269504f;
  const int jr = (lane >> 4) * 4;   // row sub-offset for this lane group
  const int lc = lane & 15;
  f32x4 c0v[2], c1v[2];
  float cav[2];
#pragma unroll
  for (int ni = 0; ni < 2; ++ni) {
    const int cloc = wc * 32 + ni * 16 + lc;
    c0v[ni] = colcc[cloc];
    c1v[ni] = colxy[cloc];
    cav[ni] = c0v[ni][2] * c0v[ni][3];
  }
  const int rrow = lane >> 2;       // readback row 0..15
  const int cg = lane & 3;          // readback col-group (8 floats each)

#pragma unroll
  for (int mi = 0; mi < 4; ++mi) {
    float* const tb = twbuf + (mi & 1) * 560;
#pragma unroll
    for (int j = 0; j < 4; ++j) {
      const int rloc = wr * 64 + mi * 16 + jr + j;
      const f32x4 r0 = rowcc[rloc];
      const f32x4 r1 = rowxy[rloc];
      const float ra = r0[2] * r0[3];
#pragma unroll
      for (int ni = 0; ni < 2; ++ni) {
        const f32x4 c0 = c0v[ni], c1 = c1v[ni];
        const float cc = fmaxf(acc[mi][ni][j], 0.0f);
        const float l1 = fabsf(r0[0] - c0[0]) + fabsf(r0[1] - c0[1]) +
                         fabsf(r0[2] - c0[2]) + fabsf(r0[3] - c0[3]);
        const float ltx = fmaxf(r1[0], c1[0]);
        const float lty = fmaxf(r1[1], c1[1]);
        const float rbx = fminf(r1[2], c1[2]);
        const float rby = fminf(r1[3], c1[3]);
        const float iw = fmaxf(rbx - ltx, 0.f);
        const float ih = fmaxf(rby - lty, 0.f);
        const float inter = iw * ih;
        const float uni = ra + cav[ni] - inter;
        const float ex = fmaxf(r1[2], c1[2]) - fminf(r1[0], c1[0]);
        const float ey = fmaxf(r1[3], c1[3]) - fminf(r1[1], c1[1]);
        const float earea = ex * ey;
        // inter/uni + uni/earea = (inter*earea + uni^2) / (uni*earea)
        const float num = fmaf(uni, uni, inter * earea);
        const float Cv = l1 + cc + 1.0f
                         - num * __builtin_amdgcn_rcpf(uni * earea);
        const float sg = __builtin_amdgcn_rcpf(
            1.0f + __builtin_amdgcn_exp2f(-LOG2E * Cv));
        tb[(jr + j) * 35 + ni * 16 + lc] = sg;
      }
    }
    // Wave-local ordering only: wait LDS writes, then transpose-read.
    asm volatile("s_waitcnt lgkmcnt(0)" ::: "memory");
    __builtin_amdgcn_sched_barrier(0);
    const f32x4 v0 = *(const f32x4*)(tb + rrow * 35 + cg * 8);
    const f32x4 v1 = *(const f32x4*)(tb + rrow * 35 + cg * 8 + 4);
    const int grow = rowBase + wr * 64 + mi * 16 + rrow;
    if (grow < N_ROWS) {
      float* const dst = out + (size_t)grow * M_COLS + colBase + wc * 32 + cg * 8;
      __builtin_nontemporal_store(v0, (f32x4*)dst);
      __builtin_nontemporal_store(v1, (f32x4*)(dst + 4));
    }
  }
}

extern "C" void kernel_launch(void* const* d_in, const int* in_sizes, int n_in,
                              void* d_out, int out_size, void* d_ws, size_t ws_size,
                              hipStream_t stream) {
  const float* logits = (const float*)d_in[0];   // [16,900,256]
  const float* pbox   = (const float*)d_in[1];   // [16,900,4]
  const float* embs   = (const float*)d_in[2];   // [1600,256]
  const float* tbox   = (const float*)d_in[3];   // [1600,4]
  float* out = (float*)d_out;                    // [16,900,1600]

  short* probB = (short*)d_ws;                         // 14400*256 bf16
  short* embB  = probB + (size_t)N_ROWS * KDIM;        // 1600*256 bf16

  prep_kernel<<<(N_ROWS + M_COLS) / 4, 256, 0, stream>>>(logits, embs, probB, embB);

  cost_kernel<<<NWG, 256, 0, stream>>>(probB, embB, pbox, tbox, out);
}

// Round 9
// 48.822 us; speedup vs baseline: 1.2752x; 1.2752x over previous
//
#include <hip/hip_runtime.h>

#define N_ROWS 14400
#define M_COLS 1600
#define KDIM   256
#define GRID_X 25           // 1600 / 64 col-tiles (exact)
#define GRID_Y 113          // ceil(14400/128) row-tiles
#define NWG    (GRID_X * GRID_Y)   // 2825

typedef __attribute__((ext_vector_type(8))) short bf16x8;
typedef __attribute__((ext_vector_type(4))) float f32x4;

__device__ __forceinline__ short f2bf(float x) {
  union { float f; unsigned u; } v; v.f = x;
  unsigned r = v.u + 0x7FFFu + ((v.u >> 16) & 1u);   // RNE to bf16
  return (short)(r >> 16);
}

__device__ __forceinline__ void gload_lds16(const void* g, void* l) {
  __builtin_amdgcn_global_load_lds(
      (const __attribute__((address_space(1))) void*)g,
      (__attribute__((address_space(3))) void*)l, 16, 0, 0);
}

// One WAVE per row; lane handles 4 consecutive floats (float4 in, short4 out).
__global__ __launch_bounds__(256) void prep_kernel(
    const float* __restrict__ logits, const float* __restrict__ embs,
    short* __restrict__ probB, short* __restrict__ embB) {
  const int row = blockIdx.x * 4 + (threadIdx.x >> 6);
  const int lane = threadIdx.x & 63;
  if (row < N_ROWS) {
    const float4 x = ((const float4*)(logits + (size_t)row * KDIM))[lane];
    float s = x.x * x.x + x.y * x.y + x.z * x.z + x.w * x.w;
#pragma unroll
    for (int o = 32; o > 0; o >>= 1) s += __shfl_xor(s, o, 64);
    const float scale = __builtin_amdgcn_rsqf(s);
    short4 o4;
    o4.x = f2bf(x.x * scale); o4.y = f2bf(x.y * scale);
    o4.z = f2bf(x.z * scale); o4.w = f2bf(x.w * scale);
    ((short4*)(probB + (size_t)row * KDIM))[lane] = o4;
  } else {
    const int r = row - N_ROWS;   // grid sized exactly, no overflow
    const float4 x = ((const float4*)(embs + (size_t)r * KDIM))[lane];
    short4 o4;
    o4.x = f2bf(x.x); o4.y = f2bf(x.y); o4.z = f2bf(x.z); o4.w = f2bf(x.w);
    ((short4*)(embB + (size_t)r * KDIM))[lane] = o4;
  }
}

// 128x64 tile GEMM (bf16 MFMA) + fused bbox-L1 + GIoU + sigmoid epilogue.
// Exactly r7's structure except the epilogue sync:
// - Ping-pong block-level transpose buf (2x 32x68 f32 in dead As+Bs):
//   one barrier per mi chunk instead of two (no overwrite hazard).
// - Barriers are lgkm-only (asm s_waitcnt lgkmcnt(0) + raw s_barrier):
//   block-wide LDS ordering preserved, but outstanding non-temporal
//   stores are NEVER drained mid-epilogue (r7's __syncthreads each forced
//   vmcnt(0) = full-HBM-latency drain of the NT store queue).
// - acc[4][2] = 32 AGPR; no min-waves clamp (r2/r4 lesson).
// - LDS GEMM tiles XOR-swizzled -> 0 bank conflicts.
// - dwordx4 NT stores, full 128B lines.
// - Bijective XCD-aware block swizzle for A-panel L2 reuse.
__global__ __launch_bounds__(256) void cost_kernel(
    const short* __restrict__ probB, const short* __restrict__ embB,
    const float* __restrict__ pbox, const float* __restrict__ tbox,
    float* __restrict__ out) {
  __shared__ short As[128 * 64];    // 16 KB; tbuf ping-pong overlays As+Bs
  __shared__ short Bs[64 * 64];     // 8 KB
  __shared__ f32x4 rowcc[128], rowxy[128];   // 4 KB
  __shared__ f32x4 colcc[64],  colxy[64];    // 2 KB
  float* const tbuf = (float*)As;   // 2 x [32][68] floats = 17408 B

  const int t = threadIdx.x;
  const int lane = t & 63;
  const int wid = t >> 6;
  const int wr = wid >> 1;          // wave row 0..1 (64-row band)
  const int wc = wid & 1;           // wave col 0..1 (32-col band)

  // Bijective XCD swizzle (m204): 8 XCDs, NWG=2825 (q=353, r=1).
  const int orig = blockIdx.x;
  const int xcd = orig & 7;
  const int rem = orig >> 3;
  const int q = NWG >> 3, r = NWG & 7;
  const int wgid = (xcd < r ? xcd * (q + 1) : r * (q + 1) + (xcd - r) * q) + rem;
  const int bx = wgid % GRID_X;
  const int by = wgid / GRID_X;
  const int rowBase = by * 128;     // N (pred) direction
  const int colBase = bx * 64;      // M (tgt) direction; always in-range

  // Stage per-tile box data (cols need no clamp: 1600 % 64 == 0).
  if (t < 128) {
    const int idx = rowBase + t;
    const int ci = idx < N_ROWS ? idx : N_ROWS - 1;
    const float4 bb = ((const float4*)pbox)[ci];
    rowcc[t] = (f32x4){bb.x, bb.y, bb.z, bb.w};
    rowxy[t] = (f32x4){fmaf(-0.5f, bb.z, bb.x), fmaf(-0.5f, bb.w, bb.y),
                       fmaf(0.5f, bb.z, bb.x), fmaf(0.5f, bb.w, bb.y)};
  } else if (t < 192) {
    const int c = t - 128;
    const float4 bb = ((const float4*)tbox)[colBase + c];
    colcc[c] = (f32x4){bb.x, bb.y, bb.z, bb.w};
    colxy[c] = (f32x4){fmaf(-0.5f, bb.z, bb.x), fmaf(-0.5f, bb.w, bb.y),
                       fmaf(0.5f, bb.z, bb.x), fmaf(0.5f, bb.w, bb.y)};
  }

  f32x4 acc[4][2];
#pragma unroll
  for (int i = 0; i < 4; ++i)
#pragma unroll
    for (int j = 0; j < 2; ++j) acc[i][j] = (f32x4){0.f, 0.f, 0.f, 0.f};

  // Pre-swizzled source granule: lane l stages granule (l&7)^(l>>3) so the
  // swizzled READ (g ^ row&7) sees linear data.
  const int swz = (lane & 7) ^ (lane >> 3);
  const int rbase = wid * 8 + (lane >> 3);   // staging row within 32-row group

  // K-loop: 4 tiles of BK=64.
  for (int kt = 0; kt < 4; ++kt) {
    const int k0 = kt * 64 + swz * 8;
#pragma unroll
    for (int i = 0; i < 4; ++i) {            // A: 128 rows
      int gr = rowBase + i * 32 + rbase;
      if (gr > N_ROWS - 1) gr = N_ROWS - 1;
      gload_lds16(probB + (size_t)gr * KDIM + k0, As + (i * 32 + wid * 8) * 64);
    }
#pragma unroll
    for (int i = 0; i < 2; ++i) {            // B: 64 rows (cols), no clamp
      const int gc = colBase + i * 32 + rbase;
      gload_lds16(embB + (size_t)gc * KDIM + k0, Bs + (i * 32 + wid * 8) * 64);
    }
    __syncthreads();
#pragma unroll
    for (int kk = 0; kk < 2; ++kk) {
      bf16x8 af[4], bfr[2];
      const int g = kk * 4 + (lane >> 4);    // 16B granule index 0..7
#pragma unroll
      for (int mi = 0; mi < 4; ++mi) {
        const int row = wr * 64 + mi * 16 + (lane & 15);
        af[mi] = *(const bf16x8*)(As + row * 64 + ((g ^ (row & 7)) * 8));
      }
#pragma unroll
      for (int ni = 0; ni < 2; ++ni) {
        const int row = wc * 32 + ni * 16 + (lane & 15);
        bfr[ni] = *(const bf16x8*)(Bs + row * 64 + ((g ^ (row & 7)) * 8));
      }
#pragma unroll
      for (int mi = 0; mi < 4; ++mi)
#pragma unroll
        for (int ni = 0; ni < 2; ++ni)
          acc[mi][ni] = __builtin_amdgcn_mfma_f32_16x16x32_bf16(
              af[mi], bfr[ni], acc[mi][ni], 0, 0, 0);
    }
    __syncthreads();   // last one also protects the tbuf overlay
  }

  // Fused epilogue. Per mi: compute+sigmoid -> tbuf[mi&1] (LDS transpose)
  // -> lgkm-only barrier -> coalesced dwordx4 NT stores (never drained).
  const float LOG2E = 1.44269504f;
  const int jr = (lane >> 4) * 4;   // row sub-offset for this lane group
  const int lc = lane & 15;
  f32x4 c0v[2], c1v[2];
  float cav[2];
#pragma unroll
  for (int ni = 0; ni < 2; ++ni) {
    const int cloc = wc * 32 + ni * 16 + lc;
    c0v[ni] = colcc[cloc];
    c1v[ni] = colxy[cloc];
    cav[ni] = c0v[ni][2] * c0v[ni][3];
  }

#pragma unroll
  for (int mi = 0; mi < 4; ++mi) {
    float* const tb = tbuf + (mi & 1) * 2176;   // 32*68 floats per buffer
#pragma unroll
    for (int j = 0; j < 4; ++j) {
      const int rloc = wr * 64 + mi * 16 + jr + j;
      const f32x4 r0 = rowcc[rloc];
      const f32x4 r1 = rowxy[rloc];
      const float ra = r0[2] * r0[3];
#pragma unroll
      for (int ni = 0; ni < 2; ++ni) {
        const f32x4 c0 = c0v[ni], c1 = c1v[ni];
        const float cc = fmaxf(acc[mi][ni][j], 0.0f);
        const float l1 = fabsf(r0[0] - c0[0]) + fabsf(r0[1] - c0[1]) +
                         fabsf(r0[2] - c0[2]) + fabsf(r0[3] - c0[3]);
        const float ltx = fmaxf(r1[0], c1[0]);
        const float lty = fmaxf(r1[1], c1[1]);
        const float rbx = fminf(r1[2], c1[2]);
        const float rby = fminf(r1[3], c1[3]);
        const float iw = fmaxf(rbx - ltx, 0.f);
        const float ih = fmaxf(rby - lty, 0.f);
        const float inter = iw * ih;
        const float uni = ra + cav[ni] - inter;
        const float ex = fmaxf(r1[2], c1[2]) - fminf(r1[0], c1[0]);
        const float ey = fmaxf(r1[3], c1[3]) - fminf(r1[1], c1[1]);
        const float earea = ex * ey;
        // inter/uni + uni/earea = (inter*earea + uni^2) / (uni*earea)
        const float num = fmaf(uni, uni, inter * earea);
        const float Cv = l1 + cc + 1.0f
                         - num * __builtin_amdgcn_rcpf(uni * earea);
        const float sg = __builtin_amdgcn_rcpf(
            1.0f + __builtin_amdgcn_exp2f(-LOG2E * Cv));
        tb[(wr * 16 + jr + j) * 68 + wc * 32 + ni * 16 + lc] = sg;
      }
    }
    // lgkm-only block barrier: LDS writes visible, NT stores keep streaming.
    asm volatile("s_waitcnt lgkmcnt(0)" ::: "memory");
    __builtin_amdgcn_s_barrier();
    // Read back transposed chunk (32 rows x 64 cols) and stream out.
#pragma unroll
    for (int rr = 0; rr < 2; ++rr) {
      const int rch = rr * 16 + (t >> 4);    // 0..31
      const int c4 = (t & 15) * 4;           // 0..60
      const f32x4 v = *(const f32x4*)(tb + rch * 68 + c4);
      const int grow = rowBase + ((rch < 16) ? (mi * 16 + rch)
                                             : (64 + mi * 16 + (rch - 16)));
      if (grow < N_ROWS)
        __builtin_nontemporal_store(
            v, (f32x4*)(out + (size_t)grow * M_COLS + colBase + c4));
    }
    // No second barrier: next mi writes the OTHER buffer; its pre-barrier
    // lgkmcnt(0) covers every wave's reads of this one.
  }
}

extern "C" void kernel_launch(void* const* d_in, const int* in_sizes, int n_in,
                              void* d_out, int out_size, void* d_ws, size_t ws_size,
                              hipStream_t stream) {
  const float* logits = (const float*)d_in[0];   // [16,900,256]
  const float* pbox   = (const float*)d_in[1];   // [16,900,4]
  const float* embs   = (const float*)d_in[2];   // [1600,256]
  const float* tbox   = (const float*)d_in[3];   // [1600,4]
  float* out = (float*)d_out;                    // [16,900,1600]

  short* probB = (short*)d_ws;                         // 14400*256 bf16
  short* embB  = probB + (size_t)N_ROWS * KDIM;        // 1600*256 bf16

  prep_kernel<<<(N_ROWS + M_COLS) / 4, 256, 0, stream>>>(logits, embs, probB, embB);

  cost_kernel<<<NWG, 256, 0, stream>>>(probB, embB, pbox, tbox, out);
}